// Round 4
// baseline (21.751 us; speedup 1.0000x reference)
//
#include <hip/hip_runtime.h>

constexpr int BB = 32;
constexpr int NN = 1024;
constexpr int HYP = 128;            // hypotheses per block
constexpr int HALF = 512;           // m-points per block (half the batch)
constexpr int WAVES = 16;
constexpr int ITERS = HALF / WAVES; // 32
#define PATCH 14.0f
#define THRSQ 25.0f   // PIXEL_THRESHOLD^2 ; sqrt(x)<=5 <=> x<=25 for correctly-rounded sqrt

// ---------------- Kernel 1: score every hypothesis ----------------
// grid = BB * 8 * 2 blocks (hyp-group g, m-half). 1024 threads = 16 waves.
// wave w handles 32 m values of this block's half; lane owns hyps n0=g*128+lane, n1=n0+64.
__global__ __launch_bounds__(1024, 8) void ransac_score_kernel(
    const float* __restrict__ src, const float* __restrict__ tar,
    const float* __restrict__ scores, const float* __restrict__ relScale,
    const float* __restrict__ relInplane, float* __restrict__ score_part)
{
#pragma clang fp contract(off)
    const int bid  = blockIdx.x;
    const int half = bid & 1;
    const int g    = (bid >> 1) & 7;
    const int b    = bid >> 4;
    const int tid  = threadIdx.x;
    const int wave = tid >> 6;
    const int lane = tid & 63;

    __shared__ float4 pts[HALF];           // (sx,sy,tx,ty)*PATCH for this half
    __shared__ float  sc[HALF];            // score, zeroed for invalid points
    __shared__ float  partial[WAVES][HYP];

    const float2* src2 = (const float2*)src + (size_t)b * NN;
    const float2* tar2 = (const float2*)tar + (size_t)b * NN;
    const float*  scb  = scores + (size_t)b * NN;
    const int mOff = half * HALF;

    if (tid < HALF) {
        float2 s = src2[mOff + tid];
        float2 t = tar2[mOff + tid];
        pts[tid] = make_float4(s.x * PATCH, s.y * PATCH, t.x * PATCH, t.y * PATCH);
        sc[tid]  = (s.x != -1.0f) ? scb[mOff + tid] : 0.0f;
    }

    // ---- hypothesis params from global (identical expressions to passing R2) ----
    const int n0 = g * HYP + lane;
    const int n1 = n0 + 64;
    const size_t nb = (size_t)b * NN;

    const float sv0 = relScale[nb + n0];
    const float sv1 = relScale[nb + n1];
    const float2 ip0 = ((const float2*)relInplane)[nb + n0];
    const float2 ip1 = ((const float2*)relInplane)[nb + n1];
    float2 s0 = src2[n0], t0 = tar2[n0];
    float2 s1 = src2[n1], t1 = tar2[n1];

    const float a00_0 = sv0 * ip0.x, a01_0 = sv0 * (-ip0.y);
    const float a10_0 = sv0 * ip0.y, a11_0 = sv0 * ip0.x;
    const float a00_1 = sv1 * ip1.x, a01_1 = sv1 * (-ip1.y);
    const float a10_1 = sv1 * ip1.y, a11_1 = sv1 * ip1.x;

    const float P0x = s0.x * PATCH, P0y = s0.y * PATCH;
    const float T0x = t0.x * PATCH, T0y = t0.y * PATCH;
    const float P1x = s1.x * PATCH, P1y = s1.y * PATCH;
    const float T1x = t1.x * PATCH, T1y = t1.y * PATCH;

    const float trx0 = T0x - (a00_0 * P0x + a01_0 * P0y);
    const float try0 = T0y - (a10_0 * P0x + a11_0 * P0y);
    const float trx1 = T1x - (a00_1 * P1x + a01_1 * P1y);
    const float try1 = T1y - (a10_1 * P1x + a11_1 * P1y);

    __syncthreads();

    float acc0 = 0.0f, acc1 = 0.0f;
    const int mBeg = wave * ITERS;
#pragma unroll 8
    for (int mm = 0; mm < ITERS; ++mm) {
        const float4 q = pts[mBeg + mm];   // same addr across wave -> LDS broadcast
        const float  w = sc[mBeg + mm];

        float px0 = a00_0 * q.x + a01_0 * q.y + trx0;
        float py0 = a10_0 * q.x + a11_0 * q.y + try0;
        float dx0 = px0 - q.z, dy0 = py0 - q.w;
        float e20 = dx0 * dx0 + dy0 * dy0;
        acc0 += (e20 <= THRSQ) ? w : 0.0f;

        float px1 = a00_1 * q.x + a01_1 * q.y + trx1;
        float py1 = a10_1 * q.x + a11_1 * q.y + try1;
        float dx1 = px1 - q.z, dy1 = py1 - q.w;
        float e21 = dx1 * dx1 + dy1 * dy1;
        acc1 += (e21 <= THRSQ) ? w : 0.0f;
    }
    partial[wave][lane]      = acc0;
    partial[wave][lane + 64] = acc1;
    __syncthreads();

    // ---- combine partials; self-term (e2~1e-8 always <=25) lives in half (g>>2) ----
    if (tid < HYP) {
        float p = 0.0f;
#pragma unroll
        for (int w = 0; w < WAVES; ++w) p += partial[w][tid];
        const int n = g * HYP + tid;
        if ((g >> 2) == half) p -= sc[n - mOff];
        score_part[((size_t)half * BB + b) * NN + n] = p;
    }
}

// ---------------- Kernel 2: argmax + M + stable inlier partition ----------------
// grid = BB blocks, 1024 threads (one per point).
__global__ __launch_bounds__(1024) void ransac_select_kernel(
    const float* __restrict__ src, const float* __restrict__ tar,
    const float* __restrict__ scores, const float* __restrict__ relScale,
    const float* __restrict__ relInplane,
    const float* __restrict__ score_part, float* __restrict__ out)
{
#pragma clang fp contract(off)
    const int b = blockIdx.x;
    const int tid = threadIdx.x;
    const int lane = tid & 63;
    const int wave = tid >> 6;

    __shared__ float wvalSh[16];
    __shared__ int   widxSh[16];
    __shared__ float prm[6];       // a00 a01 a10 a11 trx trY
    __shared__ int   bestIdxSh;
    __shared__ float bestValSh;
    __shared__ int   wcnt[16], wbase[16];
    __shared__ float osx[NN], osy[NN], otx[NN], oty[NN], osc[NN];

    const size_t gm = (size_t)b * NN + tid;
    const float2 s2 = ((const float2*)src)[gm];
    const float2 t2 = ((const float2*)tar)[gm];
    const float scin = scores[gm];

    float val;
    {
        float p = score_part[(size_t)b * NN + tid]
                + score_part[((size_t)BB + b) * NN + tid];
        val = (s2.x != -1.0f) ? p : -1.0f;
    }
    int idx = tid;

    // ---- argmax, first-index tie-break: wave butterfly then cross-wave ----
    for (int d = 1; d < 64; d <<= 1) {
        float ov = __shfl_xor(val, d);
        int   oi = __shfl_xor(idx, d);
        if (ov > val || (ov == val && oi < idx)) { val = ov; idx = oi; }
    }
    if (lane == 0) { wvalSh[wave] = val; widxSh[wave] = idx; }
    __syncthreads();
    if (tid < 64) {
        float v = (tid < 16) ? wvalSh[tid] : -1e30f;
        int   i = (tid < 16) ? widxSh[tid] : 0x7fffffff;
        for (int d = 1; d < 16; d <<= 1) {
            float ov = __shfl_xor(v, d);
            int   oi = __shfl_xor(i, d);
            if (ov > v || (ov == v && oi < i)) { v = ov; i = oi; }
        }
        if (tid == 0) { bestIdxSh = i; bestValSh = v; }
    }
    __syncthreads();
    const int best = bestIdxSh;

    if (tid == 0) {
        size_t gi = (size_t)b * NN + best;
        float scale = relScale[gi];
        float c  = relInplane[gi * 2];
        float si = relInplane[gi * 2 + 1];
        float a00 = scale * c;
        float a01 = scale * (-si);
        float a10 = scale * si;
        float a11 = scale * c;
        float snx = src[gi * 2] * PATCH, sny = src[gi * 2 + 1] * PATCH;
        float tnx = tar[gi * 2] * PATCH, tny = tar[gi * 2 + 1] * PATCH;
        float trx = tnx - (a00 * snx + a01 * sny);
        float trY = tny - (a10 * snx + a11 * sny);
        prm[0] = a00; prm[1] = a01; prm[2] = a10; prm[3] = a11; prm[4] = trx; prm[5] = trY;

        float* M = out + (size_t)b * 9;
        M[0] = a00; M[1] = a01; M[2] = trx;
        M[3] = a10; M[4] = a11; M[5] = trY;
        M[6] = 0.0f; M[7] = 0.0f; M[8] = 1.0f;
        out[(size_t)BB * 9 + b] = (bestValSh == 0.0f) ? 1.0f : 0.0f;   // failed
    }
    __syncthreads();

    // ---- recompute inlier flag for this thread's point ----
    float sx = s2.x * PATCH, sy = s2.y * PATCH;
    float tx = t2.x * PATCH, ty = t2.y * PATCH;
    float px = prm[0] * sx + prm[1] * sy + prm[4];
    float py = prm[2] * sx + prm[3] * sy + prm[5];
    float dx = px - tx, dy = py - ty;
    bool flag = (dx * dx + dy * dy <= THRSQ) && (s2.x != -1.0f) && (tid != best);

    // ---- stable exclusive prefix of flags (ballot + popcount + wave scan) ----
    unsigned long long mask = __ballot(flag);
    int posInWave = __popcll(mask & ((1ULL << lane) - 1ULL));
    if (lane == 0) wcnt[wave] = __popcll(mask);
    __syncthreads();
    if (tid < 16) {
        int s = 0;
        for (int i = 0; i < tid; ++i) s += wcnt[i];
        wbase[tid] = s;
    }
    __syncthreads();
    int pos = wbase[wave] + posInWave;

    // ---- stable partition into LDS, then coalesced write ----
    osx[tid] = -1.0f; osy[tid] = -1.0f;
    otx[tid] = -1.0f; oty[tid] = -1.0f;
    osc[tid] = 0.0f;
    __syncthreads();
    if (flag) {
        osx[pos] = s2.x; osy[pos] = s2.y;
        otx[pos] = t2.x; oty[pos] = t2.y;
        osc[pos] = scin;
    }
    __syncthreads();

    const size_t O_SRC = (size_t)BB * 9 + BB;
    const size_t O_TAR = O_SRC + (size_t)BB * NN * 2;
    const size_t O_SC  = O_TAR + (size_t)BB * NN * 2;
    out[O_SRC + gm * 2]     = osx[tid];
    out[O_SRC + gm * 2 + 1] = osy[tid];
    out[O_TAR + gm * 2]     = otx[tid];
    out[O_TAR + gm * 2 + 1] = oty[tid];
    out[O_SC  + gm]         = osc[tid];
}

extern "C" void kernel_launch(void* const* d_in, const int* in_sizes, int n_in,
                              void* d_out, int out_size, void* d_ws, size_t ws_size,
                              hipStream_t stream) {
    const float* src        = (const float*)d_in[0];
    const float* tar        = (const float*)d_in[1];
    const float* scores     = (const float*)d_in[2];
    const float* relScale   = (const float*)d_in[3];
    const float* relInplane = (const float*)d_in[4];
    float* out = (float*)d_out;
    float* score_part = (float*)d_ws;   // 2 * BB * NN floats = 256 KB

    ransac_score_kernel<<<BB * 8 * 2, 1024, 0, stream>>>(
        src, tar, scores, relScale, relInplane, score_part);
    ransac_select_kernel<<<BB, NN, 0, stream>>>(
        src, tar, scores, relScale, relInplane, score_part, out);
}

// Round 6
// 21.284 us; speedup vs baseline: 1.0219x; 1.0219x over previous
//
#include <hip/hip_runtime.h>

constexpr int BB = 32;
constexpr int NN = 1024;
constexpr int TPB = 512;            // 8 waves
constexpr int WAVES = 8;
constexpr int GH = 256;             // hypotheses per block (4 per lane)
constexpr int MQ = 256;             // m-points per block (quarter of batch)
constexpr int ITERS = MQ / WAVES;   // 32
#define PATCH 14.0f
#define THRSQ 25.0f   // PIXEL_THRESHOLD^2 ; sqrt(x)<=5 <=> x<=25 for correctly-rounded sqrt

// ---------------- Kernel 1: score every hypothesis ----------------
// grid = BB*4*4 blocks: (batch b, hyp-group g: 256 hyps, m-quarter q: 256 pts).
// 512 threads = 8 waves; wave w handles 32 m's; lane owns hyps g*256 + h*64 + lane, h=0..3.
__global__ __launch_bounds__(TPB, 3) void ransac_score_kernel(
    const float* __restrict__ src, const float* __restrict__ tar,
    const float* __restrict__ scores, const float* __restrict__ relScale,
    const float* __restrict__ relInplane, float* __restrict__ score_part)
{
#pragma clang fp contract(off)
    const int bid  = blockIdx.x;
    const int q    = bid & 3;
    const int g    = (bid >> 2) & 3;
    const int b    = bid >> 4;
    const int tid  = threadIdx.x;
    const int wave = tid >> 6;
    const int lane = tid & 63;

    __shared__ float4 pts[MQ];            // (sx,sy,tx,ty)*PATCH for this quarter
    __shared__ float  sc[MQ];             // score, zeroed for invalid points
    __shared__ float  partial[WAVES][GH];

    const float2* src2 = (const float2*)src + (size_t)b * NN;
    const float2* tar2 = (const float2*)tar + (size_t)b * NN;
    const float*  scb  = scores + (size_t)b * NN;
    const int mOff = q * MQ;

    if (tid < MQ) {
        float2 s = src2[mOff + tid];
        float2 t = tar2[mOff + tid];
        pts[tid] = make_float4(s.x * PATCH, s.y * PATCH, t.x * PATCH, t.y * PATCH);
        sc[tid]  = (s.x != -1.0f) ? scb[mOff + tid] : 0.0f;
    }

    // ---- 4 hypotheses per lane (identical expressions to passing R2/R4) ----
    const size_t nb = (size_t)b * NN;
    float a00[4], a01[4], a10[4], a11[4], trx[4], trY[4];
#pragma unroll
    for (int h = 0; h < 4; ++h) {
        const int n = g * GH + h * 64 + lane;
        const float sv  = relScale[nb + n];
        const float2 ip = ((const float2*)relInplane)[nb + n];
        float2 s = src2[n], t = tar2[n];
        a00[h] = sv * ip.x;  a01[h] = sv * (-ip.y);
        a10[h] = sv * ip.y;  a11[h] = sv * ip.x;
        const float Px = s.x * PATCH, Py = s.y * PATCH;
        const float Tx = t.x * PATCH, Ty = t.y * PATCH;
        trx[h] = Tx - (a00[h] * Px + a01[h] * Py);
        trY[h] = Ty - (a10[h] * Px + a11[h] * Py);
    }

    __syncthreads();

    float acc[4] = {0.0f, 0.0f, 0.0f, 0.0f};
    const int mBeg = wave * ITERS;
#pragma unroll 4
    for (int mm = 0; mm < ITERS; ++mm) {
        const float4 qp = pts[mBeg + mm];   // same addr across wave -> LDS broadcast
        const float  w  = sc[mBeg + mm];
#pragma unroll
        for (int h = 0; h < 4; ++h) {
            float px = a00[h] * qp.x + a01[h] * qp.y + trx[h];
            float py = a10[h] * qp.x + a11[h] * qp.y + trY[h];
            float dx = px - qp.z, dy = py - qp.w;
            float e2 = dx * dx + dy * dy;
            acc[h] += (e2 <= THRSQ) ? w : 0.0f;
        }
    }
#pragma unroll
    for (int h = 0; h < 4; ++h) partial[wave][h * 64 + lane] = acc[h];
    __syncthreads();

    // ---- combine partials; self point of hyp n lives in this block iff g==q ----
    if (tid < GH) {
        float p = 0.0f;
#pragma unroll
        for (int w = 0; w < WAVES; ++w) p += partial[w][tid];
        if (g == q) p -= sc[tid];          // self e2 ~1e-8, always counted: remove
        score_part[((size_t)q * BB + b) * NN + g * GH + tid] = p;
    }
}

// ---------------- Kernel 2: argmax + M + stable inlier partition ----------------
// grid = BB blocks, 1024 threads (one per point).
__global__ __launch_bounds__(1024) void ransac_select_kernel(
    const float* __restrict__ src, const float* __restrict__ tar,
    const float* __restrict__ scores, const float* __restrict__ relScale,
    const float* __restrict__ relInplane,
    const float* __restrict__ score_part, float* __restrict__ out)
{
#pragma clang fp contract(off)
    const int b = blockIdx.x;
    const int tid = threadIdx.x;
    const int lane = tid & 63;
    const int wave = tid >> 6;

    __shared__ float wvalSh[16];
    __shared__ int   widxSh[16];
    __shared__ float prm[6];       // a00 a01 a10 a11 trx trY
    __shared__ int   bestIdxSh;
    __shared__ float bestValSh;
    __shared__ int   wcnt[16], wbase[16];
    __shared__ float osx[NN], osy[NN], otx[NN], oty[NN], osc[NN];

    const size_t gm = (size_t)b * NN + tid;
    const float2 s2 = ((const float2*)src)[gm];
    const float2 t2 = ((const float2*)tar)[gm];
    const float scin = scores[gm];

    float val;
    {
        float p = score_part[(size_t)b * NN + tid]
                + score_part[((size_t)BB + b) * NN + tid]
                + score_part[((size_t)2 * BB + b) * NN + tid]
                + score_part[((size_t)3 * BB + b) * NN + tid];
        val = (s2.x != -1.0f) ? p : -1.0f;
    }
    int idx = tid;

    // ---- argmax, first-index tie-break: wave butterfly then cross-wave ----
    for (int d = 1; d < 64; d <<= 1) {
        float ov = __shfl_xor(val, d);
        int   oi = __shfl_xor(idx, d);
        if (ov > val || (ov == val && oi < idx)) { val = ov; idx = oi; }
    }
    if (lane == 0) { wvalSh[wave] = val; widxSh[wave] = idx; }
    __syncthreads();
    if (tid < 64) {
        float v = (tid < 16) ? wvalSh[tid] : -1e30f;
        int   i = (tid < 16) ? widxSh[tid] : 0x7fffffff;
        for (int d = 1; d < 16; d <<= 1) {
            float ov = __shfl_xor(v, d);
            int   oi = __shfl_xor(i, d);
            if (ov > v || (ov == v && oi < i)) { v = ov; i = oi; }
        }
        if (tid == 0) { bestIdxSh = i; bestValSh = v; }
    }
    __syncthreads();
    const int best = bestIdxSh;

    if (tid == 0) {
        size_t gi = (size_t)b * NN + best;
        float scale = relScale[gi];
        float c  = relInplane[gi * 2];
        float si = relInplane[gi * 2 + 1];
        float a00 = scale * c;
        float a01 = scale * (-si);
        float a10 = scale * si;
        float a11 = scale * c;
        float snx = src[gi * 2] * PATCH, sny = src[gi * 2 + 1] * PATCH;
        float tnx = tar[gi * 2] * PATCH, tny = tar[gi * 2 + 1] * PATCH;
        float trx = tnx - (a00 * snx + a01 * sny);
        float trY = tny - (a10 * snx + a11 * sny);
        prm[0] = a00; prm[1] = a01; prm[2] = a10; prm[3] = a11; prm[4] = trx; prm[5] = trY;

        float* M = out + (size_t)b * 9;
        M[0] = a00; M[1] = a01; M[2] = trx;
        M[3] = a10; M[4] = a11; M[5] = trY;
        M[6] = 0.0f; M[7] = 0.0f; M[8] = 1.0f;
        out[(size_t)BB * 9 + b] = (bestValSh == 0.0f) ? 1.0f : 0.0f;   // failed
    }
    __syncthreads();

    // ---- recompute inlier flag for this thread's point ----
    float sx = s2.x * PATCH, sy = s2.y * PATCH;
    float tx = t2.x * PATCH, ty = t2.y * PATCH;
    float px = prm[0] * sx + prm[1] * sy + prm[4];
    float py = prm[2] * sx + prm[3] * sy + prm[5];
    float dx = px - tx, dy = py - ty;
    bool flag = (dx * dx + dy * dy <= THRSQ) && (s2.x != -1.0f) && (tid != best);

    // ---- stable exclusive prefix of flags (ballot + popcount + wave scan) ----
    unsigned long long mask = __ballot(flag);
    int posInWave = __popcll(mask & ((1ULL << lane) - 1ULL));
    if (lane == 0) wcnt[wave] = __popcll(mask);
    __syncthreads();
    if (tid < 16) {
        int s = 0;
        for (int i = 0; i < tid; ++i) s += wcnt[i];
        wbase[tid] = s;
    }
    __syncthreads();
    int pos = wbase[wave] + posInWave;

    // ---- stable partition into LDS, then coalesced write ----
    osx[tid] = -1.0f; osy[tid] = -1.0f;
    otx[tid] = -1.0f; oty[tid] = -1.0f;
    osc[tid] = 0.0f;
    __syncthreads();
    if (flag) {
        osx[pos] = s2.x; osy[pos] = s2.y;
        otx[pos] = t2.x; oty[pos] = t2.y;
        osc[pos] = scin;
    }
    __syncthreads();

    const size_t O_SRC = (size_t)BB * 9 + BB;
    const size_t O_TAR = O_SRC + (size_t)BB * NN * 2;
    const size_t O_SC  = O_TAR + (size_t)BB * NN * 2;
    out[O_SRC + gm * 2]     = osx[tid];
    out[O_SRC + gm * 2 + 1] = osy[tid];
    out[O_TAR + gm * 2]     = otx[tid];
    out[O_TAR + gm * 2 + 1] = oty[tid];
    out[O_SC  + gm]         = osc[tid];
}

extern "C" void kernel_launch(void* const* d_in, const int* in_sizes, int n_in,
                              void* d_out, int out_size, void* d_ws, size_t ws_size,
                              hipStream_t stream) {
    const float* src        = (const float*)d_in[0];
    const float* tar        = (const float*)d_in[1];
    const float* scores     = (const float*)d_in[2];
    const float* relScale   = (const float*)d_in[3];
    const float* relInplane = (const float*)d_in[4];
    float* out = (float*)d_out;
    float* score_part = (float*)d_ws;   // 4 * BB * NN floats = 512 KB

    ransac_score_kernel<<<BB * 4 * 4, TPB, 0, stream>>>(
        src, tar, scores, relScale, relInplane, score_part);
    ransac_select_kernel<<<BB, NN, 0, stream>>>(
        src, tar, scores, relScale, relInplane, score_part, out);
}

// Round 7
// 19.182 us; speedup vs baseline: 1.1339x; 1.1096x over previous
//
#include <hip/hip_runtime.h>

constexpr int BB = 32;
constexpr int NN = 1024;
constexpr int TPB = 512;            // 8 waves
constexpr int WAVES = 8;
constexpr int GH = 256;             // hypotheses per block (4 per lane)
constexpr int MQ = 256;             // m-points per block (quarter of batch)
constexpr int ITERS = MQ / WAVES;   // 32
#define PATCH 14.0f
#define THRSQ 25.0f   // PIXEL_THRESHOLD^2 ; sqrt(x)<=5 <=> x<=25 for correctly-rounded sqrt

// ---------------- Kernel 1: score every hypothesis ----------------
// grid = BB*4*4 blocks: (batch b, hyp-group g: 256 hyps, m-quarter q: 256 pts).
// 512 threads = 8 waves; wave w handles 32 m's; lane owns hyps g*256 + h*64 + lane, h=0..3.
// Inner loop uses EXPLICIT fmaf (11 VALU/eval vs 16): scores only feed argmax;
// kernel2 recomputes the winning hyp's inliers with exact contract-off arithmetic.
__global__ __launch_bounds__(TPB, 3) void ransac_score_kernel(
    const float* __restrict__ src, const float* __restrict__ tar,
    const float* __restrict__ scores, const float* __restrict__ relScale,
    const float* __restrict__ relInplane, float* __restrict__ score_part)
{
#pragma clang fp contract(off)
    const int bid  = blockIdx.x;
    const int q    = bid & 3;
    const int g    = (bid >> 2) & 3;
    const int b    = bid >> 4;
    const int tid  = threadIdx.x;
    const int wave = tid >> 6;
    const int lane = tid & 63;

    __shared__ float4 pts[MQ];            // (sx,sy,tx,ty)*PATCH for this quarter
    __shared__ float  sc[MQ];             // score, zeroed for invalid points
    __shared__ float  partial[WAVES][GH];

    const float2* src2 = (const float2*)src + (size_t)b * NN;
    const float2* tar2 = (const float2*)tar + (size_t)b * NN;
    const float*  scb  = scores + (size_t)b * NN;
    const int mOff = q * MQ;

    if (tid < MQ) {
        float2 s = src2[mOff + tid];
        float2 t = tar2[mOff + tid];
        pts[tid] = make_float4(s.x * PATCH, s.y * PATCH, t.x * PATCH, t.y * PATCH);
        sc[tid]  = (s.x != -1.0f) ? scb[mOff + tid] : 0.0f;
    }

    // ---- 4 hypotheses per lane (exact contract-off preamble, unchanged) ----
    const size_t nb = (size_t)b * NN;
    float a00[4], a01[4], a10[4], a11[4], trx[4], trY[4];
#pragma unroll
    for (int h = 0; h < 4; ++h) {
        const int n = g * GH + h * 64 + lane;
        const float sv  = relScale[nb + n];
        const float2 ip = ((const float2*)relInplane)[nb + n];
        float2 s = src2[n], t = tar2[n];
        a00[h] = sv * ip.x;  a01[h] = sv * (-ip.y);
        a10[h] = sv * ip.y;  a11[h] = sv * ip.x;
        const float Px = s.x * PATCH, Py = s.y * PATCH;
        const float Tx = t.x * PATCH, Ty = t.y * PATCH;
        trx[h] = Tx - (a00[h] * Px + a01[h] * Py);
        trY[h] = Ty - (a10[h] * Px + a11[h] * Py);
    }

    __syncthreads();

    float acc[4] = {0.0f, 0.0f, 0.0f, 0.0f};
    const int mBeg = wave * ITERS;
#pragma unroll 4
    for (int mm = 0; mm < ITERS; ++mm) {
        const float4 qp = pts[mBeg + mm];   // same addr across wave -> LDS broadcast
        const float  w  = sc[mBeg + mm];
#pragma unroll
        for (int h = 0; h < 4; ++h) {
            // fused form: 11 VALU issues/eval (scoring only — argmax input)
            float px = __builtin_fmaf(a00[h], qp.x, __builtin_fmaf(a01[h], qp.y, trx[h]));
            float py = __builtin_fmaf(a10[h], qp.x, __builtin_fmaf(a11[h], qp.y, trY[h]));
            float dx = px - qp.z, dy = py - qp.w;
            float e2 = __builtin_fmaf(dx, dx, dy * dy);
            acc[h] += (e2 <= THRSQ) ? w : 0.0f;
        }
    }
#pragma unroll
    for (int h = 0; h < 4; ++h) partial[wave][h * 64 + lane] = acc[h];
    __syncthreads();

    // ---- combine partials; self point of hyp n lives in this block iff g==q ----
    if (tid < GH) {
        float p = 0.0f;
#pragma unroll
        for (int w = 0; w < WAVES; ++w) p += partial[w][tid];
        if (g == q) p -= sc[tid];          // self e2 ~1e-8, always counted: remove
        score_part[((size_t)q * BB + b) * NN + g * GH + tid] = p;
    }
}

// ---------------- Kernel 2: argmax + M + stable inlier partition ----------------
// grid = BB blocks, 1024 threads (one per point). EXACT arithmetic (contract off).
__global__ __launch_bounds__(1024) void ransac_select_kernel(
    const float* __restrict__ src, const float* __restrict__ tar,
    const float* __restrict__ scores, const float* __restrict__ relScale,
    const float* __restrict__ relInplane,
    const float* __restrict__ score_part, float* __restrict__ out)
{
#pragma clang fp contract(off)
    const int b = blockIdx.x;
    const int tid = threadIdx.x;
    const int lane = tid & 63;
    const int wave = tid >> 6;

    __shared__ float wvalSh[16];
    __shared__ int   widxSh[16];
    __shared__ float prm[6];       // a00 a01 a10 a11 trx trY
    __shared__ int   bestIdxSh;
    __shared__ float bestValSh;
    __shared__ int   wcnt[16], wbase[16];
    __shared__ float osx[NN], osy[NN], otx[NN], oty[NN], osc[NN];

    const size_t gm = (size_t)b * NN + tid;
    const float2 s2 = ((const float2*)src)[gm];
    const float2 t2 = ((const float2*)tar)[gm];
    const float scin = scores[gm];

    float val;
    {
        float p = score_part[(size_t)b * NN + tid]
                + score_part[((size_t)BB + b) * NN + tid]
                + score_part[((size_t)2 * BB + b) * NN + tid]
                + score_part[((size_t)3 * BB + b) * NN + tid];
        val = (s2.x != -1.0f) ? p : -1.0f;
    }
    int idx = tid;

    // ---- argmax, first-index tie-break: wave butterfly then cross-wave ----
    for (int d = 1; d < 64; d <<= 1) {
        float ov = __shfl_xor(val, d);
        int   oi = __shfl_xor(idx, d);
        if (ov > val || (ov == val && oi < idx)) { val = ov; idx = oi; }
    }
    if (lane == 0) { wvalSh[wave] = val; widxSh[wave] = idx; }
    __syncthreads();
    if (tid < 64) {
        float v = (tid < 16) ? wvalSh[tid] : -1e30f;
        int   i = (tid < 16) ? widxSh[tid] : 0x7fffffff;
        for (int d = 1; d < 16; d <<= 1) {
            float ov = __shfl_xor(v, d);
            int   oi = __shfl_xor(i, d);
            if (ov > v || (ov == v && oi < i)) { v = ov; i = oi; }
        }
        if (tid == 0) { bestIdxSh = i; bestValSh = v; }
    }
    __syncthreads();
    const int best = bestIdxSh;

    if (tid == 0) {
        size_t gi = (size_t)b * NN + best;
        float scale = relScale[gi];
        float c  = relInplane[gi * 2];
        float si = relInplane[gi * 2 + 1];
        float a00 = scale * c;
        float a01 = scale * (-si);
        float a10 = scale * si;
        float a11 = scale * c;
        float snx = src[gi * 2] * PATCH, sny = src[gi * 2 + 1] * PATCH;
        float tnx = tar[gi * 2] * PATCH, tny = tar[gi * 2 + 1] * PATCH;
        float trx = tnx - (a00 * snx + a01 * sny);
        float trY = tny - (a10 * snx + a11 * sny);
        prm[0] = a00; prm[1] = a01; prm[2] = a10; prm[3] = a11; prm[4] = trx; prm[5] = trY;

        float* M = out + (size_t)b * 9;
        M[0] = a00; M[1] = a01; M[2] = trx;
        M[3] = a10; M[4] = a11; M[5] = trY;
        M[6] = 0.0f; M[7] = 0.0f; M[8] = 1.0f;
        out[(size_t)BB * 9 + b] = (bestValSh == 0.0f) ? 1.0f : 0.0f;   // failed
    }
    __syncthreads();

    // ---- recompute inlier flag for this thread's point (exact sequence) ----
    float sx = s2.x * PATCH, sy = s2.y * PATCH;
    float tx = t2.x * PATCH, ty = t2.y * PATCH;
    float px = prm[0] * sx + prm[1] * sy + prm[4];
    float py = prm[2] * sx + prm[3] * sy + prm[5];
    float dx = px - tx, dy = py - ty;
    bool flag = (dx * dx + dy * dy <= THRSQ) && (s2.x != -1.0f) && (tid != best);

    // ---- stable exclusive prefix of flags (ballot + popcount + wave scan) ----
    unsigned long long mask = __ballot(flag);
    int posInWave = __popcll(mask & ((1ULL << lane) - 1ULL));
    if (lane == 0) wcnt[wave] = __popcll(mask);
    __syncthreads();
    if (tid < 16) {
        int s = 0;
        for (int i = 0; i < tid; ++i) s += wcnt[i];
        wbase[tid] = s;
    }
    __syncthreads();
    int pos = wbase[wave] + posInWave;

    // ---- stable partition into LDS, then coalesced write ----
    osx[tid] = -1.0f; osy[tid] = -1.0f;
    otx[tid] = -1.0f; oty[tid] = -1.0f;
    osc[tid] = 0.0f;
    __syncthreads();
    if (flag) {
        osx[pos] = s2.x; osy[pos] = s2.y;
        otx[pos] = t2.x; oty[pos] = t2.y;
        osc[pos] = scin;
    }
    __syncthreads();

    const size_t O_SRC = (size_t)BB * 9 + BB;
    const size_t O_TAR = O_SRC + (size_t)BB * NN * 2;
    const size_t O_SC  = O_TAR + (size_t)BB * NN * 2;
    out[O_SRC + gm * 2]     = osx[tid];
    out[O_SRC + gm * 2 + 1] = osy[tid];
    out[O_TAR + gm * 2]     = otx[tid];
    out[O_TAR + gm * 2 + 1] = oty[tid];
    out[O_SC  + gm]         = osc[tid];
}

extern "C" void kernel_launch(void* const* d_in, const int* in_sizes, int n_in,
                              void* d_out, int out_size, void* d_ws, size_t ws_size,
                              hipStream_t stream) {
    const float* src        = (const float*)d_in[0];
    const float* tar        = (const float*)d_in[1];
    const float* scores     = (const float*)d_in[2];
    const float* relScale   = (const float*)d_in[3];
    const float* relInplane = (const float*)d_in[4];
    float* out = (float*)d_out;
    float* score_part = (float*)d_ws;   // 4 * BB * NN floats = 512 KB

    ransac_score_kernel<<<BB * 4 * 4, TPB, 0, stream>>>(
        src, tar, scores, relScale, relInplane, score_part);
    ransac_select_kernel<<<BB, NN, 0, stream>>>(
        src, tar, scores, relScale, relInplane, score_part, out);
}